// Round 5
// baseline (89.271 us; speedup 1.0000x reference)
//
#include <hip/hip_runtime.h>

#define B_    32
#define N_    10000
#define G_    256
#define HID_  256
#define Z_    256
#define EPS_  1e-5f

// prep_k grid segmentation
#define TB_W1  2504            // 313 col-tiles x 8 row-tiles (W1: 256 x 10000)
#define TB_X   313             // x: 32 x 10000
#define TB_W2  64              // W2: 256 x 256
#define NB_CMP 256             // mask compaction, one block per g
#define PREP_GRID (TB_W1 + TB_X + TB_W2 + NB_CMP)   // 3137

#define NSPB_  1020            // sparse blocks: 255 groups x 4 quarters
#define DKB_   80              // dense-group split-K blocks
#define DCH_   125             // genes per dense chunk (80*125 = 10000)

// ---------------------------------------------------------------------------
// Tiled transpose helper: src R x C row-major -> dst C x R row-major.
// ---------------------------------------------------------------------------
__device__ inline void transpose_tile(const float* __restrict__ src,
                                      float* __restrict__ dst,
                                      int R, int C, int bx, int by, int t,
                                      float (*tile)[33]) {
    int tx = t & 31, ty = t >> 5;      // 32 x 8
    int c0 = bx * 32, r0 = by * 32;
#pragma unroll
    for (int j = 0; j < 4; ++j) {
        int r = r0 + ty + j * 8, c = c0 + tx;
        if (r < R && c < C) tile[ty + j * 8][tx] = src[(size_t)r * C + c];
    }
    __syncthreads();
#pragma unroll
    for (int j = 0; j < 4; ++j) {
        int c = c0 + ty + j * 8, r = r0 + tx;
        if (r < R && c < C) dst[(size_t)c * R + r] = tile[tx][ty + j * 8];
    }
}

// ---------------------------------------------------------------------------
// Fused prep: W1/x/W2 transposes + mask compaction (per-group gene lists).
// ---------------------------------------------------------------------------
__global__ __launch_bounds__(256) void prep_k(const float* __restrict__ W1,
                                              const float* __restrict__ x,
                                              const float* __restrict__ W2,
                                              const float* __restrict__ mask,
                                              float* __restrict__ w1t,
                                              float* __restrict__ xt,
                                              float* __restrict__ w2t,
                                              int* __restrict__ cnt,
                                              unsigned short* __restrict__ idx) {
    __shared__ float tile[32][33];
    __shared__ int c;
    int bid = blockIdx.x, t = threadIdx.x;

    if (bid < TB_W1) {
        transpose_tile(W1, w1t, HID_, N_, bid % 313, bid / 313, t, tile);
    } else if (bid < TB_W1 + TB_X) {
        transpose_tile(x, xt, B_, N_, bid - TB_W1, 0, t, tile);
    } else if (bid < TB_W1 + TB_X + TB_W2) {
        int b = bid - (TB_W1 + TB_X);
        transpose_tile(W2, w2t, Z_, HID_, b % 8, b / 8, t, tile);
    } else {
        int g = bid - (TB_W1 + TB_X + TB_W2);
        if (t == 0) c = 0;
        __syncthreads();
        for (int n = t; n < N_; n += 256) {
            if (mask[(size_t)g * N_ + n] != 0.0f) {
                int p = atomicAdd(&c, 1);          // LDS atomic only
                idx[(size_t)g * N_ + p] = (unsigned short)n;
            }
        }
        __syncthreads();
        if (t == 0) cnt[g] = c;
    }
}

// ---------------------------------------------------------------------------
// Sparse group-GEMM, zero atomics, 256 threads = 4 waves.
//   tc = t & 63  -> float4 HID column; wave spans full 1KB W-row (coalesced)
//   tb = t >> 6  -> batches 8tb..8tb+7 (wave-uniform -> xs LDS broadcast)
// bid < 1020: quarter (bid&3) of group (bid>>2) -> hpartS[bid] (32x256 tile).
// bid >= 1020: dense chunk of group 255 (contiguous genes, no idx) -> hpartD.
// Per gene per thread: 1 indep float4 load + 2 LDS broadcasts + 32 fmaf.
// ---------------------------------------------------------------------------
__global__ __launch_bounds__(256) void spgemm_k(const float4* __restrict__ w1t4,
                                                const float4* __restrict__ xt4,
                                                const int* __restrict__ cnt,
                                                const unsigned short* __restrict__ idx,
                                                float4* __restrict__ hpartS,
                                                float4* __restrict__ hpartD) {
    __shared__ int ns[128];
    __shared__ float4 xs[128][9];      // [gene][b/4] + pad
    const int bid = blockIdx.x, t = threadIdx.x;
    const int tc = t & 63;
    const int tb = t >> 6;

    int g = 255, k0, kend;
    bool dense;
    float4* dst;
    if (bid < NSPB_) {
        g = bid >> 2;
        int c = cnt[g];
        int L = (c + 3) >> 2;
        k0 = (bid & 3) * L;
        kend = min(c, k0 + L);
        dst = hpartS + (size_t)bid * 2048;
        dense = false;
    } else {
        int kb = bid - NSPB_;
        k0 = kb * DCH_;
        kend = k0 + DCH_;
        dst = hpartD + (size_t)kb * 2048;
        dense = true;
    }

    float4 a0 = {0.f, 0.f, 0.f, 0.f}, a1 = a0, a2 = a0, a3 = a0;
    float4 a4 = a0, a5 = a0, a6 = a0, a7 = a0;

    for (int base = k0; base < kend; base += 128) {
        int kn = min(128, kend - base);
        __syncthreads();                           // protect ns/xs reuse
        if (!dense) {
            if (t < kn) ns[t] = idx[(size_t)g * N_ + base + t];
            __syncthreads();
        }
        for (int i = t; i < kn * 8; i += 256) {
            int k = i >> 3, q = i & 7;
            int n = dense ? (base + k) : ns[k];
            xs[k][q] = xt4[(size_t)n * 8 + q];
        }
        __syncthreads();

#pragma unroll 4
        for (int k = 0; k < kn; ++k) {
            int n = dense ? (base + k) : ns[k];
            float4 wv = w1t4[(size_t)n * 64 + tc];   // 1KB/wave, coalesced
            float4 xa = xs[k][2 * tb];                // LDS broadcast
            float4 xb = xs[k][2 * tb + 1];
            a0.x = fmaf(xa.x, wv.x, a0.x); a0.y = fmaf(xa.x, wv.y, a0.y);
            a0.z = fmaf(xa.x, wv.z, a0.z); a0.w = fmaf(xa.x, wv.w, a0.w);
            a1.x = fmaf(xa.y, wv.x, a1.x); a1.y = fmaf(xa.y, wv.y, a1.y);
            a1.z = fmaf(xa.y, wv.z, a1.z); a1.w = fmaf(xa.y, wv.w, a1.w);
            a2.x = fmaf(xa.z, wv.x, a2.x); a2.y = fmaf(xa.z, wv.y, a2.y);
            a2.z = fmaf(xa.z, wv.z, a2.z); a2.w = fmaf(xa.z, wv.w, a2.w);
            a3.x = fmaf(xa.w, wv.x, a3.x); a3.y = fmaf(xa.w, wv.y, a3.y);
            a3.z = fmaf(xa.w, wv.z, a3.z); a3.w = fmaf(xa.w, wv.w, a3.w);
            a4.x = fmaf(xb.x, wv.x, a4.x); a4.y = fmaf(xb.x, wv.y, a4.y);
            a4.z = fmaf(xb.x, wv.z, a4.z); a4.w = fmaf(xb.x, wv.w, a4.w);
            a5.x = fmaf(xb.y, wv.x, a5.x); a5.y = fmaf(xb.y, wv.y, a5.y);
            a5.z = fmaf(xb.y, wv.z, a5.z); a5.w = fmaf(xb.y, wv.w, a5.w);
            a6.x = fmaf(xb.z, wv.x, a6.x); a6.y = fmaf(xb.z, wv.y, a6.y);
            a6.z = fmaf(xb.z, wv.z, a6.z); a6.w = fmaf(xb.z, wv.w, a6.w);
            a7.x = fmaf(xb.w, wv.x, a7.x); a7.y = fmaf(xb.w, wv.y, a7.y);
            a7.z = fmaf(xb.w, wv.z, a7.z); a7.w = fmaf(xb.w, wv.w, a7.w);
        }
    }

    dst[(size_t)(8 * tb + 0) * 64 + tc] = a0;
    dst[(size_t)(8 * tb + 1) * 64 + tc] = a1;
    dst[(size_t)(8 * tb + 2) * 64 + tc] = a2;
    dst[(size_t)(8 * tb + 3) * 64 + tc] = a3;
    dst[(size_t)(8 * tb + 4) * 64 + tc] = a4;
    dst[(size_t)(8 * tb + 5) * 64 + tc] = a5;
    dst[(size_t)(8 * tb + 6) * 64 + tc] = a6;
    dst[(size_t)(8 * tb + 7) * 64 + tc] = a7;
}

// ---------------------------------------------------------------------------
// Dense-group split-K reduction: h255[i] = b1 + sum_kb hpartD[kb][i]
// ---------------------------------------------------------------------------
__global__ __launch_bounds__(256) void reduce_k(const float* __restrict__ hpartD,
                                                const float* __restrict__ b1,
                                                float* __restrict__ h255) {
    int i = blockIdx.x * 256 + threadIdx.x;   // 0..8191
    float s = b1[i & (HID_ - 1)];
#pragma unroll 8
    for (int kb = 0; kb < DKB_; ++kb) s += hpartD[(size_t)kb * (B_ * HID_) + i];
    h255[i] = s;
}

// ---------------------------------------------------------------------------
// Fused (sum 4 sparse partials + b1) -> BN1+ReLU -> GEMM2 -> BN2+ReLU.
// One block per group g, 512 threads. GEMM mapping: tc=t&63 (full 1KB
// coalesced W2 row per wave), rg=t>>6 (rows 4rg..4rg+3, LDS broadcast).
// ---------------------------------------------------------------------------
__global__ __launch_bounds__(512) void fused_k(const float4* __restrict__ hpartS,
                                               const float4* __restrict__ h255_4,
                                               const float4* __restrict__ w2t4,
                                               const float4* __restrict__ b1_4,
                                               const float* __restrict__ g1,
                                               const float* __restrict__ be1,
                                               const float4* __restrict__ b2_4,
                                               const float* __restrict__ g2,
                                               const float* __restrict__ be2,
                                               float4* __restrict__ z4) {
    __shared__ float lh[32][260];      // 32 rows(b) x 256(c), pad to 65 float4
    __shared__ float rs[8], rss[8];
    const int g = blockIdx.x, t = threadIdx.x;
    const int w = t >> 6, l = t & 63;
    const int tc = l;                  // float4 z-col (0..63), per-wave full row
    const int rg = w;                  // rows 4rg..4rg+3

    // ---- load + sum partials (coalesced), accumulate BN1 stats ----
    float s = 0.f, ss = 0.f;
    float4 mine[4];
    const float4* p0 = hpartS + (size_t)g * 4 * 2048;
#pragma unroll
    for (int p = 0; p < 4; ++p) {
        int i = p * 512 + t;                   // 0..2047
        int r = i >> 6, q = i & 63;
        float4 v;
        if (g < 255) {
            float4 v0 = p0[i], v1 = p0[2048 + i], v2 = p0[4096 + i], v3 = p0[6144 + i];
            float4 bb = b1_4[q];
            v.x = v0.x + v1.x + v2.x + v3.x + bb.x;
            v.y = v0.y + v1.y + v2.y + v3.y + bb.y;
            v.z = v0.z + v1.z + v2.z + v3.z + bb.z;
            v.w = v0.w + v1.w + v2.w + v3.w + bb.w;
        } else {
            v = h255_4[i];                     // b1 already added by reduce_k
        }
        mine[p] = v;
        *(float4*)&lh[r][4 * q] = v;
        s  += v.x + v.y + v.z + v.w;
        ss += v.x * v.x + v.y * v.y + v.z * v.z + v.w * v.w;
    }
#pragma unroll
    for (int o = 32; o > 0; o >>= 1) { s += __shfl_down(s, o); ss += __shfl_down(ss, o); }
    if (l == 0) { rs[w] = s; rss[w] = ss; }
    __syncthreads();
    float S = 0.f, SS = 0.f;
#pragma unroll
    for (int j = 0; j < 8; ++j) { S += rs[j]; SS += rss[j]; }
    const float inv = 1.0f / (float)(B_ * HID_);
    float mean = S * inv;
    float var  = SS * inv - mean * mean;
    float sc = g1[g] * rsqrtf(var + EPS_);
    float sh = be1[g] - mean * sc;

    // ---- normalize + ReLU own elements in LDS ----
#pragma unroll
    for (int p = 0; p < 4; ++p) {
        int i = p * 512 + t;
        int r = i >> 6, q = i & 63;
        float4 v = mine[p];
        v.x = fmaxf(fmaf(v.x, sc, sh), 0.f);
        v.y = fmaxf(fmaf(v.y, sc, sh), 0.f);
        v.z = fmaxf(fmaf(v.z, sc, sh), 0.f);
        v.w = fmaxf(fmaf(v.w, sc, sh), 0.f);
        *(float4*)&lh[r][4 * q] = v;
    }
    __syncthreads();

    // ---- GEMM2: acc[j] = z rows 4rg+j, z-cols 4tc..4tc+3 ----
    float4 bb = b2_4[tc];
    float4 acc[4] = {bb, bb, bb, bb};
#pragma unroll 8
    for (int k = 0; k < HID_; ++k) {
        float4 wv = w2t4[(size_t)k * 64 + tc];         // 1KB/wave, coalesced
#pragma unroll
        for (int j = 0; j < 4; ++j) {
            float xv = lh[4 * rg + j][k];              // LDS broadcast
            acc[j].x = fmaf(xv, wv.x, acc[j].x);
            acc[j].y = fmaf(xv, wv.y, acc[j].y);
            acc[j].z = fmaf(xv, wv.z, acc[j].z);
            acc[j].w = fmaf(xv, wv.w, acc[j].w);
        }
    }

    // ---- BN2 stats over the block's 8192 acc values ----
    s = 0.f; ss = 0.f;
#pragma unroll
    for (int j = 0; j < 4; ++j) {
        s  += acc[j].x + acc[j].y + acc[j].z + acc[j].w;
        ss += acc[j].x * acc[j].x + acc[j].y * acc[j].y
            + acc[j].z * acc[j].z + acc[j].w * acc[j].w;
    }
#pragma unroll
    for (int o = 32; o > 0; o >>= 1) { s += __shfl_down(s, o); ss += __shfl_down(ss, o); }
    if (l == 0) { rs[w] = s; rss[w] = ss; }   // safe: BN1 rs reads are pre-GEMM sync
    __syncthreads();
    S = 0.f; SS = 0.f;
#pragma unroll
    for (int j = 0; j < 8; ++j) { S += rs[j]; SS += rss[j]; }
    mean = S * inv;
    var  = SS * inv - mean * mean;
    float sc2 = g2[g] * rsqrtf(var + EPS_);
    float sh2 = be2[g] - mean * sc2;

    // ---- BN2 + ReLU + store to out[b, g, z] ----
#pragma unroll
    for (int j = 0; j < 4; ++j) {
        int b = 4 * rg + j;
        float4 v;
        v.x = fmaxf(fmaf(acc[j].x, sc2, sh2), 0.f);
        v.y = fmaxf(fmaf(acc[j].y, sc2, sh2), 0.f);
        v.z = fmaxf(fmaf(acc[j].z, sc2, sh2), 0.f);
        v.w = fmaxf(fmaf(acc[j].w, sc2, sh2), 0.f);
        z4[(size_t)(b * G_ + g) * 64 + tc] = v;
    }
}

// ---------------------------------------------------------------------------
extern "C" void kernel_launch(void* const* d_in, const int* in_sizes, int n_in,
                              void* d_out, int out_size, void* d_ws, size_t ws_size,
                              hipStream_t stream) {
    const float* x    = (const float*)d_in[0];
    const float* mask = (const float*)d_in[1];
    const float* W1   = (const float*)d_in[2];
    const float* b1   = (const float*)d_in[3];
    const float* g1   = (const float*)d_in[4];
    const float* be1  = (const float*)d_in[5];
    const float* W2   = (const float*)d_in[6];
    const float* b2   = (const float*)d_in[7];
    const float* g2   = (const float*)d_in[8];
    const float* be2  = (const float*)d_in[9];
    float* out = (float*)d_out;

    char* ws = (char*)d_ws;
    size_t off = 0;
    auto take = [&](size_t bytes) {
        char* p = ws + off;
        off = (off + bytes + 255) & ~(size_t)255;
        return p;
    };
    float* w1t          = (float*)take((size_t)N_ * HID_ * 4);       // (N, HID)
    float* xt           = (float*)take((size_t)N_ * B_ * 4);         // (N, B)
    float* w2t          = (float*)take((size_t)HID_ * Z_ * 4);       // (HID, Z)
    float* hpartS       = (float*)take((size_t)NSPB_ * B_ * HID_ * 4);
    float* hpartD       = (float*)take((size_t)DKB_ * B_ * HID_ * 4);
    float* h255         = (float*)take((size_t)B_ * HID_ * 4);
    int* cnt            = (int*)take((size_t)G_ * 4);
    unsigned short* idx = (unsigned short*)take((size_t)G_ * N_ * 2);

    prep_k<<<PREP_GRID, 256, 0, stream>>>(W1, x, W2, mask, w1t, xt, w2t, cnt, idx);
    spgemm_k<<<NSPB_ + DKB_, 256, 0, stream>>>((const float4*)w1t, (const float4*)xt,
                                               cnt, idx, (float4*)hpartS, (float4*)hpartD);
    reduce_k<<<(B_ * HID_) / 256, 256, 0, stream>>>(hpartD, b1, h255);
    fused_k<<<G_, 512, 0, stream>>>((const float4*)hpartS, (const float4*)h255,
                                    (const float4*)w2t, (const float4*)b1,
                                    g1, be1, (const float4*)b2, g2, be2,
                                    (float4*)out);
}